// Round 1
// baseline (117.650 us; speedup 1.0000x reference)
//
#include <hip/hip_runtime.h>

// Problem: InteractionNet  B=8, N1=256, N2=256, F=128
// All inputs/outputs fp32 (per reference dtypes).
//
// R5: halve L2 weight traffic by doubling rows/block.
//   k_lin:   8 rows/block, 512 blocks  -> W reads 64MB -> 32MB L2
//   k_fused: 8 rows/block, 256 blocks  -> GRU weight reads 196MB -> 98MB L2
//            (each of threads 0..383 owns exactly one wih row + one whh row,
//             applied to all 8 tile rows; gate combine via LDS transpose)
// Measurement note: dur_us window includes harness 256MB ws poison fills
// (~3x41.5us); kernel-side total is the remaining ~12us we are shrinking.

#define FDIM 128
#define N2DIM 256

// ---------------- Kernel 1: m1 = x1 @ W_w^T + W_b ; Mx2 = x2 @ M_w^T + M_b ----
// 8 rows per block, 128 thr; blocks 0..255 -> m1, 256..511 -> Mx2.
// 512 blocks = 2 blocks/CU. Each weight row read exactly once per block.
__global__ __launch_bounds__(128)
void k_lin(const float* __restrict__ x1,
           const float* __restrict__ x2,
           const float* __restrict__ Ww,
           const float* __restrict__ Wb,
           const float* __restrict__ Mw,
           const float* __restrict__ Mb,
           float* __restrict__ m1, float* __restrict__ mx2)
{
  int blk = blockIdx.x;
  int which = blk >> 8;
  int row0 = (blk & 255) << 3;
  const float* X  = which ? x2 : x1;
  const float* W  = which ? Mw : Ww;
  const float* Bv = which ? Mb : Wb;
  float* out = which ? mx2 : m1;

  __shared__ float xs[8][FDIM];
  int tid = threadIdx.x;  // = output column g
#pragma unroll
  for (int r = 0; r < 8; ++r)
    xs[r][tid] = X[(size_t)(row0 + r) * FDIM + tid];
  __syncthreads();

  const float* wrow = W + (size_t)tid * FDIM;
  float acc[8];
#pragma unroll
  for (int r = 0; r < 8; ++r) acc[r] = 0.f;

  for (int k0 = 0; k0 < FDIM; k0 += 4) {
    float4 wv = *(const float4*)(wrow + k0);
#pragma unroll
    for (int r = 0; r < 8; ++r) {
      float4 xv = *(const float4*)(&xs[r][k0]);   // LDS broadcast, conflict-free
      acc[r] += xv.x * wv.x + xv.y * wv.y + xv.z * wv.z + xv.w * wv.w;
    }
  }
  float bv = Bv[tid];
#pragma unroll
  for (int r = 0; r < 8; ++r)
    out[(size_t)(row0 + r) * FDIM + tid] = acc[r] + bv;
}

// ---------------- Kernel 2 (fused): masked-max + relu + GRUCell -------------
// 8 rows (same b) per block, 512 threads, 256 blocks = 1 block/CU (8 waves).
// Phases: [A] preload x1 tile + compact valid-j lists (64 lanes/row)
//         [B] m2 = max over valid j of Mx2[b,j,f]; x = relu(m1+m2) -> LDS
//             (thread (q=tid>>7, f) handles rows {q, q+4} — 2 rows, 8-deep MLP,
//              identical per-thread shape to the proven R4 kernel)
//         [C] GRU GEMM: threads 0..383, (g=tid>>7, f=tid&127) own wih row
//             g*128+f (vs x) and whh row g*128+f (vs x1), all 8 tile rows.
//             16 indep accumulators/thread; weight rows unique per block.
//         [D] gate combine from LDS sums, 2 rows/thread.
// Mask is exactly 0.0/1.0: product==value for valid j; any zero mask
// contributes a 0 term to the max (nz flag).
__global__ __launch_bounds__(512)
void k_fused(const float* __restrict__ ve,
             const float* __restrict__ mx2,
             const float* __restrict__ m1,
             const float* __restrict__ x1,
             const float* __restrict__ wih,
             const float* __restrict__ whh,
             const float* __restrict__ bih,
             const float* __restrict__ bhh,
             float* __restrict__ out)
{
  int row0 = blockIdx.x << 3;      // 8 consecutive global rows, same b
  int b = row0 >> 8;
  int tid = threadIdx.x;

  __shared__ float x_sh[8][FDIM];        // GRU input x
  __shared__ float h_sh[8][FDIM];        // hidden = x1 rows
  __shared__ float si_sh[3][8][FDIM];    // gi sums (+bias)
  __shared__ float sh_sh[3][8][FDIM];    // gh sums (+bias)
  __shared__ int idx[8][N2DIM];
  __shared__ int cnt[8];
  __shared__ int nz[8];

  // [A] preload x1 tile (global loads overlap compaction below)
  for (int t = tid; t < 8 * FDIM; t += 512)
    h_sh[t >> 7][t & 127] = x1[(size_t)row0 * FDIM + t];
  if (tid < 8) { cnt[tid] = 0; nz[tid] = 0; }
  __syncthreads();

  {
    int r = tid >> 6, l = tid & 63;      // 64 lanes compact one row's mask
    const float* e = ve + (size_t)(row0 + r) * N2DIM;
#pragma unroll
    for (int j0 = 0; j0 < N2DIM; j0 += 64) {
      float v = e[j0 + l];
      if (v != 0.0f) { int p = atomicAdd(&cnt[r], 1); idx[r][p] = j0 + l; }
      else nz[r] = 1;
    }
  }
  __syncthreads();

  // [B] masked max + relu; thread (q,f) handles rows {q, q+4}
  {
    int q = tid >> 7, f = tid & 127;
    const float* Mbase = mx2 + (size_t)b * N2DIM * FDIM + f;
#pragma unroll
    for (int rr = 0; rr < 2; ++rr) {
      int r = q + (rr << 2);
      int n = cnt[r];
      const int* ix = idx[r];
      float m2 = nz[r] ? 0.0f : -3.0e38f;
      int i = 0;
      for (; i + 8 <= n; i += 8) {       // 8 L2 loads in flight
        float v0 = Mbase[(size_t)ix[i]     * FDIM];
        float v1 = Mbase[(size_t)ix[i + 1] * FDIM];
        float v2 = Mbase[(size_t)ix[i + 2] * FDIM];
        float v3 = Mbase[(size_t)ix[i + 3] * FDIM];
        float v4 = Mbase[(size_t)ix[i + 4] * FDIM];
        float v5 = Mbase[(size_t)ix[i + 5] * FDIM];
        float v6 = Mbase[(size_t)ix[i + 6] * FDIM];
        float v7 = Mbase[(size_t)ix[i + 7] * FDIM];
        m2 = fmaxf(m2, fmaxf(fmaxf(fmaxf(v0, v1), fmaxf(v2, v3)),
                             fmaxf(fmaxf(v4, v5), fmaxf(v6, v7))));
      }
      for (; i < n; ++i)
        m2 = fmaxf(m2, Mbase[(size_t)ix[i] * FDIM]);
      float s = m1[(size_t)(row0 + r) * FDIM + f] + m2;
      x_sh[r][f] = fmaxf(s, 0.0f);
    }
  }
  __syncthreads();

  // [C] GRU GEMM — threads 0..383; each owns one wih row AND one whh row
  if (tid < 384) {
    int g = tid >> 7, f = tid & 127;     // gate g, output column f
    const float* wi = wih + (size_t)(g * 128 + f) * FDIM;
    const float* wh = whh + (size_t)(g * 128 + f) * FDIM;

    float ai[8], ah[8];
#pragma unroll
    for (int r = 0; r < 8; ++r) { ai[r] = 0.f; ah[r] = 0.f; }

    for (int k0 = 0; k0 < FDIM; k0 += 4) {
      float4 wiv = *(const float4*)(wi + k0);
      float4 whv = *(const float4*)(wh + k0);
#pragma unroll
      for (int r = 0; r < 8; ++r) {
        float4 xv = *(const float4*)(&x_sh[r][k0]);   // LDS broadcast
        float4 hv = *(const float4*)(&h_sh[r][k0]);
        ai[r] += xv.x * wiv.x + xv.y * wiv.y + xv.z * wiv.z + xv.w * wiv.w;
        ah[r] += hv.x * whv.x + hv.y * whv.y + hv.z * whv.z + hv.w * whv.w;
      }
    }
    float bi = bih[g * 128 + f];
    float bh = bhh[g * 128 + f];
#pragma unroll
    for (int r = 0; r < 8; ++r) {
      si_sh[g][r][f] = ai[r] + bi;
      sh_sh[g][r][f] = ah[r] + bh;
    }
  }
  __syncthreads();

  // [D] gates; thread (q,f) handles rows {q, q+4}
  {
    int q = tid >> 7, f = tid & 127;
#pragma unroll
    for (int rr = 0; rr < 2; ++rr) {
      int r = q + (rr << 2);
      float ir  = si_sh[0][r][f];
      float iz  = si_sh[1][r][f];
      float in_ = si_sh[2][r][f];
      float hr  = sh_sh[0][r][f];
      float hz  = sh_sh[1][r][f];
      float hn  = sh_sh[2][r][f];
      float rg  = 1.f / (1.f + __expf(-(ir + hr)));
      float zg  = 1.f / (1.f + __expf(-(iz + hz)));
      float pre = in_ + rg * hn;
      float e2  = __expf(2.f * pre);
      float nn  = 1.f - 2.f / (e2 + 1.f);   // tanh(pre)
      float h   = (1.f - zg) * nn + zg * h_sh[r][f];
      out[(size_t)(row0 + r) * FDIM + f] = h;
    }
  }
}

extern "C" void kernel_launch(void* const* d_in, const int* in_sizes, int n_in,
                              void* d_out, int out_size, void* d_ws, size_t ws_size,
                              hipStream_t stream) {
  (void)in_sizes; (void)n_in; (void)out_size; (void)ws_size;
  const float* x1  = (const float*)d_in[0];
  const float* x2  = (const float*)d_in[1];
  const float* ve  = (const float*)d_in[2];
  const float* Ww  = (const float*)d_in[3];
  const float* Wb  = (const float*)d_in[4];
  const float* Mw  = (const float*)d_in[5];
  const float* Mb  = (const float*)d_in[6];
  const float* wih = (const float*)d_in[7];
  const float* whh = (const float*)d_in[8];
  const float* bih = (const float*)d_in[9];
  const float* bhh = (const float*)d_in[10];
  float* out = (float*)d_out;

  float* ws  = (float*)d_ws;
  float* m1  = ws;               // 262144 floats
  float* mx2 = ws + 262144;      // 262144 floats

  hipLaunchKernelGGL(k_lin,   dim3(512), dim3(128), 0, stream,
                     x1, x2, Ww, Wb, Mw, Mb, m1, mx2);
  hipLaunchKernelGGL(k_fused, dim3(256), dim3(512), 0, stream,
                     ve, mx2, m1, x1, wih, whh, bih, bhh, out);
}